// Round 1
// baseline (450.697 us; speedup 1.0000x reference)
//
#include <hip/hip_runtime.h>

// QuadratureFunction: out[c,q] = sum_b local_dofs[c,b] * y[c,b,q]
// local_dofs = [3 vertex gathers | 3 edges x 2 dofs (flipped if orient==0) | face dof]
// C = 500000, NB = 10, Q = 16.
//
// Layout: 4 lanes per cell; lane l computes out[c, 4l..4l+3] as float4.
// y loads: float4 at (c*40 + b*4 + l) -> 64B contiguous per (c,b) quad-group.

#define NBASIS 10

__global__ __launch_bounds__(256) void quad_kernel(
    const float*  __restrict__ vertex_dofs,   // [V,1]
    const float*  __restrict__ edge_dofs,     // [E,2]
    const float*  __restrict__ face_dofs,     // [C,1]
    const float4* __restrict__ y4,            // [C,10,16] viewed as float4[C*40]
    const int*    __restrict__ faces,         // [C,3]
    const int*    __restrict__ f2e,           // [C,3]
    const int*    __restrict__ orient,        // [C,3]
    float4*       __restrict__ out4,          // [C,16] viewed as float4[C*4]
    int C)
{
    int t = blockIdx.x * blockDim.x + threadIdx.x;
    int c = t >> 2;          // cell
    if (c >= C) return;
    int l = t & 3;           // quarter of the Q=16 row

    float ld[NBASIS];

    // vertex dofs (DV=1)
    #pragma unroll
    for (int j = 0; j < 3; ++j) {
        ld[j] = vertex_dofs[faces[3 * c + j]];
    }

    // edge dofs (DE=2), flip order when orientation == 0
    #pragma unroll
    for (int j = 0; j < 3; ++j) {
        int e = f2e[3 * c + j];
        int o = orient[3 * c + j];
        float e0 = edge_dofs[2 * e + 0];
        float e1 = edge_dofs[2 * e + 1];
        ld[3 + 2 * j + 0] = o ? e0 : e1;
        ld[3 + 2 * j + 1] = o ? e1 : e0;
    }

    // face dof (DF=1)
    ld[9] = face_dofs[c];

    // weighted sum over basis functions
    const float4* yp = y4 + (size_t)c * 40 + l;
    float4 acc = make_float4(0.f, 0.f, 0.f, 0.f);
    #pragma unroll
    for (int b = 0; b < NBASIS; ++b) {
        float4 v = yp[(size_t)b * 4];
        acc.x = fmaf(ld[b], v.x, acc.x);
        acc.y = fmaf(ld[b], v.y, acc.y);
        acc.z = fmaf(ld[b], v.z, acc.z);
        acc.w = fmaf(ld[b], v.w, acc.w);
    }

    out4[(size_t)c * 4 + l] = acc;
}

extern "C" void kernel_launch(void* const* d_in, const int* in_sizes, int n_in,
                              void* d_out, int out_size, void* d_ws, size_t ws_size,
                              hipStream_t stream) {
    const float*  vertex_dofs = (const float*)d_in[0];
    const float*  edge_dofs   = (const float*)d_in[1];
    const float*  face_dofs   = (const float*)d_in[2];
    const float4* y4          = (const float4*)d_in[3];
    const int*    faces       = (const int*)d_in[4];
    const int*    f2e         = (const int*)d_in[5];
    const int*    orient      = (const int*)d_in[6];
    float4*       out4        = (float4*)d_out;

    const int C = in_sizes[2];            // face_dofs has C*DF = C elements
    const int threads = C * 4;            // 4 lanes per cell
    const int block = 256;
    const int grid = (threads + block - 1) / block;

    quad_kernel<<<grid, block, 0, stream>>>(vertex_dofs, edge_dofs, face_dofs,
                                            y4, faces, f2e, orient, out4, C);
}